// Round 1
// baseline (934.100 us; speedup 1.0000x reference)
//
#include <hip/hip_runtime.h>
#include <hip/hip_bf16.h>
#include <math.h>

// Problem constants
#define BB 4
#define C_IN 256
#define HH 256
#define WW 256
#define LL 5000
#define N_PTS0 32
#define N_PTS1 8
#define DIM_LOI 128
#define DIM_FC 1024
#define N_OUT_LINE 2500
#define MM (BB * LL)          // 20000
#define PIX (HH * WW)         // 65536

typedef __attribute__((ext_vector_type(8))) short short8_t;   // 8 bf16 in 4 VGPRs
typedef __attribute__((ext_vector_type(4))) float float4v;

// float -> bf16 (RNE) bit tricks
__device__ __forceinline__ short f2bf(float f) {
    union { float f; unsigned u; } c; c.f = f;
    unsigned u = c.u;
    u += 0x7FFFu + ((u >> 16) & 1u);
    return (short)(u >> 16);
}
__device__ __forceinline__ float bf2f(short h) {
    union { unsigned u; float f; } c; c.u = ((unsigned)(unsigned short)h) << 16;
    return c.f;
}

// async global->LDS DMA, 16 B per lane; dest = wave-uniform base + lane*16
__device__ __forceinline__ void load_lds16(const void* g, void* l) {
    __builtin_amdgcn_global_load_lds(
        (const __attribute__((address_space(1))) void*)g,
        (__attribute__((address_space(3))) void*)l, 16, 0, 0);
}

// raw barrier (NO vmcnt drain) + compiler-level memory fence so LDS reads
// can't be hoisted above it at IR level
__device__ __forceinline__ void wave_barrier() {
    asm volatile("" ::: "memory");
    __builtin_amdgcn_s_barrier();
    asm volatile("" ::: "memory");
}

#define MFMA_B16(a, b, c) \
    c = __builtin_amdgcn_mfma_f32_16x16x32_bf16(a, b, c, 0, 0, 0)

// ---------------------------------------------------------------------------
// Kernel 1: 1x1 conv as bf16x3 MFMA GEMM (unchanged).
// ---------------------------------------------------------------------------
__global__ __launch_bounds__(256) void conv_mfma_kernel(
    const float* __restrict__ feat,   // [B, 256, PIX]
    const short* __restrict__ whi,    // [128, 256] bf16 hi
    const short* __restrict__ wlo,    // [128, 256] bf16 lo
    const float* __restrict__ bias,   // [128]
    float* __restrict__ x)            // [B*PIX, 128]
{
    __shared__ short As_hi[128][40];
    __shared__ short As_lo[128][40];
    __shared__ short Ws_hi[128][40];
    __shared__ short Ws_lo[128][40];

    const int t  = threadIdx.x;
    const int m0 = blockIdx.x * 128;
    const int b  = m0 >> 16;
    const int p0 = m0 & (PIX - 1);
    const float* fb = feat + (size_t)b * C_IN * PIX + p0;

    const int w = t >> 6, lane = t & 63;
    const int wmb = (w >> 1) * 64, wnb = (w & 1) * 64;
    const int fr = lane & 15;
    const int koff = (lane >> 4) << 3;

    const int sp = t & 127;
    const int cg = t >> 7;

    float4v acc[4][4];
#pragma unroll
    for (int mi = 0; mi < 4; mi++)
#pragma unroll
        for (int ni = 0; ni < 4; ni++)
            acc[mi][ni] = (float4v){0.f, 0.f, 0.f, 0.f};

    for (int k0 = 0; k0 < C_IN; k0 += 32) {
#pragma unroll
        for (int i = 0; i < 2; i++) {
            int idx = t + (i << 8);
            int row = idx >> 2;
            int kc  = (idx & 3) << 3;
            *(int4*)&Ws_hi[row][kc] = *(const int4*)(whi + row * C_IN + k0 + kc);
            *(int4*)&Ws_lo[row][kc] = *(const int4*)(wlo + row * C_IN + k0 + kc);
        }
#pragma unroll
        for (int j = 0; j < 8; j++) {
            int c = cg * 16 + j * 2;
            float v0 = fb[(size_t)(k0 + c) * PIX + sp];
            float v1 = fb[(size_t)(k0 + c + 1) * PIX + sp];
            short h0 = f2bf(v0), h1 = f2bf(v1);
            short l0 = f2bf(v0 - bf2f(h0)), l1 = f2bf(v1 - bf2f(h1));
            *(unsigned*)&As_hi[sp][c] =
                (unsigned)(unsigned short)h0 | ((unsigned)(unsigned short)h1 << 16);
            *(unsigned*)&As_lo[sp][c] =
                (unsigned)(unsigned short)l0 | ((unsigned)(unsigned short)l1 << 16);
        }
        __syncthreads();

        short8_t ah[4], al[4];
#pragma unroll
        for (int mi = 0; mi < 4; mi++) {
            ah[mi] = *(const short8_t*)&As_hi[wmb + mi * 16 + fr][koff];
            al[mi] = *(const short8_t*)&As_lo[wmb + mi * 16 + fr][koff];
        }
#pragma unroll
        for (int ni = 0; ni < 4; ni++) {
            short8_t bh = *(const short8_t*)&Ws_hi[wnb + ni * 16 + fr][koff];
            short8_t bl = *(const short8_t*)&Ws_lo[wnb + ni * 16 + fr][koff];
#pragma unroll
            for (int mi = 0; mi < 4; mi++) {
                MFMA_B16(ah[mi], bh, acc[mi][ni]);
                MFMA_B16(al[mi], bh, acc[mi][ni]);
                MFMA_B16(ah[mi], bl, acc[mi][ni]);
            }
        }
        __syncthreads();
    }

#pragma unroll
    for (int ni = 0; ni < 4; ni++) {
        int ncol = wnb + ni * 16 + fr;
        float bv = bias[ncol];
#pragma unroll
        for (int mi = 0; mi < 4; mi++) {
            int r0 = m0 + wmb + mi * 16 + ((lane >> 4) << 2);
#pragma unroll
            for (int i2 = 0; i2 < 4; i2++) {
                x[(size_t)(r0 + i2) * 128 + ncol] = acc[mi][ni][i2] + bv;
            }
        }
    }
}

// ---------------------------------------------------------------------------
// Kernel 2: bilinear sample + maxpool -> bf16 hi/lo pooled (unchanged).
// ---------------------------------------------------------------------------
__global__ __launch_bounds__(128) void sample_pool_kernel(
    const float* __restrict__ lines,
    const float* __restrict__ x,
    short* __restrict__ phi,
    short* __restrict__ plo)
{
    const int bl = blockIdx.x;
    const int b  = bl / LL;
    const int c  = threadIdx.x;
    const float* lp = lines + (size_t)bl * 4;
    const float p0r = lp[0], p0c = lp[1], p1r = lp[2], p1c = lp[3];
    const float* xb = x + (size_t)b * PIX * 128;

    short8_t vh, vl;
#pragma unroll
    for (int g = 0; g < 8; g++) {
        float mx = -INFINITY;
#pragma unroll
        for (int j = 0; j < 4; j++) {
            int tt = g * 4 + j;
            float lam = (float)((double)tt / 31.0);
            float px = p0r * lam + p1r * (1.0f - lam) - 0.5f;
            float py = p0c * lam + p1c * (1.0f - lam) - 0.5f;
            float px0 = fminf(fmaxf(floorf(px), 0.0f), 255.0f);
            float py0 = fminf(fmaxf(floorf(py), 0.0f), 255.0f);
            float px1 = fminf(px0 + 1.0f, 255.0f);
            float py1 = fminf(py0 + 1.0f, 255.0f);
            int ix0 = (int)px0, iy0 = (int)py0, ix1 = (int)px1, iy1 = (int)py1;
            float wx1 = px1 - px, wx0 = px - px0;
            float wy1 = py1 - py, wy0 = py - py0;
            float v00 = xb[(size_t)(ix0 * WW + iy0) * 128 + c];
            float v10 = xb[(size_t)(ix1 * WW + iy0) * 128 + c];
            float v01 = xb[(size_t)(ix0 * WW + iy1) * 128 + c];
            float v11 = xb[(size_t)(ix1 * WW + iy1) * 128 + c];
            float v = v00 * (wx1 * wy1) + v10 * (wx0 * wy1)
                    + v01 * (wx1 * wy0) + v11 * (wx0 * wy0);
            mx = fmaxf(mx, v);
        }
        short h = f2bf(mx);
        vh[g] = h;
        vl[g] = f2bf(mx - bf2f(h));
    }
    *(short8_t*)(phi + (size_t)bl * 1024 + c * 8) = vh;
    *(short8_t*)(plo + (size_t)bl * 1024 + c * 8) = vl;
}

// ---------------------------------------------------------------------------
// Kernel 2b: split fp32 weights into bf16 hi/lo (unchanged).
// ---------------------------------------------------------------------------
__global__ __launch_bounds__(256) void split_kernel(
    const float* __restrict__ w, short* __restrict__ hi, short* __restrict__ lo)
{
    const int i = (blockIdx.x * 256 + threadIdx.x) * 4;
    float4 v = *(const float4*)(w + i);
    float vv[4] = {v.x, v.y, v.z, v.w};
    short4 h, l;
    short hs[4], ls[4];
#pragma unroll
    for (int j = 0; j < 4; j++) {
        hs[j] = f2bf(vv[j]);
        ls[j] = f2bf(vv[j] - bf2f(hs[j]));
    }
    h.x = hs[0]; h.y = hs[1]; h.z = hs[2]; h.w = hs[3];
    l.x = ls[0]; l.y = ls[1]; l.z = ls[2]; l.w = ls[3];
    *(short4*)(hi + i) = h;
    *(short4*)(lo + i) = l;
}

// ---------------------------------------------------------------------------
// Kernel 3 v3: bf16x3 MFMA GEMM-NT with counted-vmcnt pipeline (T2+T3+T4+T5).
//
//  Tile 256(M) x 128(N), BK=32, 512 threads (8 waves, 4M x 2N wave grid),
//  per-wave 64x64 output (acc[4][4]).
//  LDS: 3 buffers x 48 KB = 144 KB -> prefetch depth 2 (tile t computes while
//       t+1 is landed and t+2 is in flight). Never vmcnt(0) in steady state:
//       end-of-tile s_waitcnt vmcnt(6) + raw s_barrier publishes buf t+1
//       while t+2's 6 DMA chunks stay outstanding.
//  4 phases per K-tile (one per M-frag; B hi/lo frags held for whole tile):
//       {2 DMA issues | ds_reads -> barrier -> lgkmcnt(0)+sched_barrier(0)
//        -> setprio(1) -> 12 MFMA -> setprio(0) -> barrier}
//  T2 swizzle (both-sides, rule 21): linear DMA dest, global SOURCE chunk
//       pre-permuted c^((row>>1)&3), same XOR on the ds_read chunk. Both fold
//       to per-lane constants (csrc, ksw) -> zero loop-time VALU.
//       Read pattern goes 8-way -> 2-way bank aliasing (free per m136).
//  Bijective XCD map: grid = Mtiles*8; bid&7 = XCD gets a contiguous run of
//       M-panels x all 8 N-tiles (B hi/lo = 4 MB stays L2-resident per XCD).
// ---------------------------------------------------------------------------
#define NT 32                 // K tiles (1024 / 32)
#define BUF_SHORTS 24576      // 48 KB per buffer
// per-buffer mat offsets (shorts): Ahi 0 (8192), Alo 8192, Bhi 16384 (4096), Blo 20480

template <bool SPLIT_OUT>
__global__ __launch_bounds__(512, 2) void gemm_bf16x3_v3(
    const short* __restrict__ Ahi, const short* __restrict__ Alo,
    const short* __restrict__ Bhi, const short* __restrict__ Blo,
    const float* __restrict__ bias,
    float* __restrict__ Cf, short* __restrict__ Chi, short* __restrict__ Clo,
    int M, int Mtiles)
{
    __shared__ short lds[3 * BUF_SHORTS];   // 144 KB

    const int t    = threadIdx.x;
    const int bid  = blockIdx.x;
    // bijective XCD swizzle: XCD (bid&7) owns wgids [xcd*Mtiles, (xcd+1)*Mtiles)
    const int wgid  = (bid & 7) * Mtiles + (bid >> 3);
    const int tileM = wgid >> 3;
    const int tileN = wgid & 7;
    const int m0 = tileM * 256, n0 = tileN * 128;

    const int w = t >> 6, lane = t & 63;
    const int wmb = (w >> 1) * 64;          // 0,64,128,192 (M)
    const int wnb = (w & 1) * 64;           // 0,64 (N)
    const int fr = lane & 15;
    // swizzled read chunk (shorts): (c ^ ((row>>1)&3))*8, row ≡ fr (mod 16)
    const int ksw = (((lane >> 4) ^ ((lane >> 1) & 3)) << 3);
    const int a_base = (wmb + fr) * 32 + ksw;            // Ahi frag base
    const int b_base = 16384 + (wnb + fr) * 32 + ksw;    // Bhi frag base

    // --- staging descriptors: 6 DMA slots per wave, 48 slots = 48 KB/K-tile
    const short* gp[6];
    int lp[6];
    {
        const int csrc = (lane & 3) ^ ((lane >> 3) & 3);  // source chunk permute
#pragma unroll
        for (int s = 0; s < 6; s++) {
            int e = w * 6 + s;                            // 0..47
            int m_ = (e < 16) ? 0 : (e < 32) ? 1 : (e < 40) ? 2 : 3;
            int j  = e - ((m_ == 0) ? 0 : (m_ == 1) ? 16 : (m_ == 2) ? 32 : 40);
            const short* mp = (m_ == 0) ? Ahi : (m_ == 1) ? Alo
                            : (m_ == 2) ? Bhi : Blo;
            int mo = (m_ == 0) ? 0 : (m_ == 1) ? 8192
                   : (m_ == 2) ? 16384 : 20480;
            int row  = j * 16 + (lane >> 2);
            int grow = (m_ < 2) ? min(m0 + row, M - 1) : (n0 + row);
            gp[s] = mp + (size_t)grow * 1024 + csrc * 8;
            lp[s] = mo + j * 512 + lane * 8;              // lane0 = wave base
        }
    }

    // --- prologue: stage T0 -> buf0, T1 -> buf1; wait T0 only
#pragma unroll
    for (int s = 0; s < 6; s++) { load_lds16(gp[s], &lds[lp[s]]); gp[s] += 32; }
#pragma unroll
    for (int s = 0; s < 6; s++) { load_lds16(gp[s], &lds[BUF_SHORTS + lp[s]]); gp[s] += 32; }
    asm volatile("s_waitcnt vmcnt(6)" ::: "memory");
    wave_barrier();

    float4v acc[4][4];
#pragma unroll
    for (int mi = 0; mi < 4; mi++)
#pragma unroll
        for (int ni = 0; ni < 4; ni++)
            acc[mi][ni] = (float4v){0.f, 0.f, 0.f, 0.f};

    int off_cur = 0, off_nxt = BUF_SHORTS, off_pre = 2 * BUF_SHORTS;

    for (int kt = 0; kt < NT; ++kt) {
        const bool pf = (kt + 2 < NT);

        // ---- phase 0: B hi/lo frags (whole tile) + A frag mi=0
        short8_t bh[4], bl[4];
#pragma unroll
        for (int ni = 0; ni < 4; ni++) {
            bh[ni] = *(const short8_t*)&lds[off_cur + b_base + ni * 512];
            bl[ni] = *(const short8_t*)&lds[off_cur + b_base + ni * 512 + 4096];
        }
        short8_t ah = *(const short8_t*)&lds[off_cur + a_base];
        short8_t al = *(const short8_t*)&lds[off_cur + a_base + 8192];
        if (pf) {
            load_lds16(gp[0], &lds[off_pre + lp[0]]); gp[0] += 32;
            load_lds16(gp[1], &lds[off_pre + lp[1]]); gp[1] += 32;
        }
        wave_barrier();
        asm volatile("s_waitcnt lgkmcnt(0)" ::: "memory");
        __builtin_amdgcn_sched_barrier(0);
        __builtin_amdgcn_s_setprio(1);
#pragma unroll
        for (int ni = 0; ni < 4; ni++) {
            MFMA_B16(ah, bh[ni], acc[0][ni]);
            MFMA_B16(al, bh[ni], acc[0][ni]);
            MFMA_B16(ah, bl[ni], acc[0][ni]);
        }
        __builtin_amdgcn_s_setprio(0);
        wave_barrier();

        // ---- phases 1..3: A frag mi, reuse bh/bl
#pragma unroll
        for (int mi = 1; mi < 4; mi++) {
            ah = *(const short8_t*)&lds[off_cur + a_base + mi * 512];
            al = *(const short8_t*)&lds[off_cur + a_base + mi * 512 + 8192];
            if (pf && mi < 3) {
                load_lds16(gp[2 * mi],     &lds[off_pre + lp[2 * mi]]);     gp[2 * mi]     += 32;
                load_lds16(gp[2 * mi + 1], &lds[off_pre + lp[2 * mi + 1]]); gp[2 * mi + 1] += 32;
            }
            wave_barrier();
            asm volatile("s_waitcnt lgkmcnt(0)" ::: "memory");
            __builtin_amdgcn_sched_barrier(0);
            __builtin_amdgcn_s_setprio(1);
#pragma unroll
            for (int ni = 0; ni < 4; ni++) {
                MFMA_B16(ah, bh[ni], acc[mi][ni]);
                MFMA_B16(al, bh[ni], acc[mi][ni]);
                MFMA_B16(ah, bl[ni], acc[mi][ni]);
            }
            __builtin_amdgcn_s_setprio(0);
            if (mi < 3) wave_barrier();
        }

        // ---- tile end: publish buf for t+1; keep t+2's 6 loads in flight
        if (pf) asm volatile("s_waitcnt vmcnt(6)" ::: "memory");
        else    asm volatile("s_waitcnt vmcnt(0)" ::: "memory");
        wave_barrier();
        int tmp = off_cur; off_cur = off_nxt; off_nxt = off_pre; off_pre = tmp;
    }

    // ---- epilogue
#pragma unroll
    for (int ni = 0; ni < 4; ni++) {
        int ncol = n0 + wnb + ni * 16 + fr;
        float bv = bias[ncol];
#pragma unroll
        for (int mi = 0; mi < 4; mi++) {
            int r0 = m0 + wmb + mi * 16 + ((lane >> 4) << 2);
#pragma unroll
            for (int i2 = 0; i2 < 4; i2++) {
                int r = r0 + i2;
                if (r < M) {
                    float v = fmaxf(acc[mi][ni][i2] + bv, 0.0f);
                    if (SPLIT_OUT) {
                        short h = f2bf(v);
                        Chi[(size_t)r * 1024 + ncol] = h;
                        Clo[(size_t)r * 1024 + ncol] = f2bf(v - bf2f(h));
                    } else {
                        Cf[(size_t)r * 1024 + ncol] = v;
                    }
                }
            }
        }
    }
}

// ---------------------------------------------------------------------------
// Kernel 4: fc3 (N=4) + softmax + mask + argmax-class key (unchanged).
// ---------------------------------------------------------------------------
__global__ __launch_bounds__(256) void fc3_softmax_kernel(
    const float* __restrict__ h2, const float* __restrict__ w3,
    const float* __restrict__ b3, float* __restrict__ s, int* __restrict__ keys)
{
    const int m = blockIdx.x * 4 + (threadIdx.x >> 6);
    const int lane = threadIdx.x & 63;
    const float* hp = h2 + (size_t)m * DIM_FC;
    float a0 = 0.f, a1 = 0.f, a2 = 0.f, a3 = 0.f;
    for (int k = lane; k < DIM_FC; k += 64) {
        float hv = hp[k];
        a0 = fmaf(hv, w3[k], a0);
        a1 = fmaf(hv, w3[DIM_FC + k], a1);
        a2 = fmaf(hv, w3[2 * DIM_FC + k], a2);
        a3 = fmaf(hv, w3[3 * DIM_FC + k], a3);
    }
#pragma unroll
    for (int off = 32; off > 0; off >>= 1) {
        a0 += __shfl_down(a0, off, 64);
        a1 += __shfl_down(a1, off, 64);
        a2 += __shfl_down(a2, off, 64);
        a3 += __shfl_down(a3, off, 64);
    }
    if (lane == 0) {
        float l0 = a0 + b3[0], l1 = a1 + b3[1], l2 = a2 + b3[2], l3 = a3 + b3[3];
        float mxl = fmaxf(fmaxf(l0, l1), fmaxf(l2, l3));
        float e0 = expf(l0 - mxl), e1 = expf(l1 - mxl);
        float e2 = expf(l2 - mxl), e3 = expf(l3 - mxl);
        float inv = 1.0f / (e0 + e1 + e2 + e3);
        float s0 = e0 * inv, s1 = e1 * inv, s2 = e2 * inv, s3 = e3 * inv;
        float* sp = s + (size_t)m * 4;
        sp[0] = s0; sp[1] = s1; sp[2] = s2; sp[3] = s3;
        int best = 0; float bv = s0;
        if (s1 > bv) { best = 1; bv = s1; }
        if (s2 > bv) { best = 2; bv = s2; }
        if (s3 > bv) { best = 3; bv = s3; }
        bool msk = ((s1 > 0.25f) || (s2 > 0.25f) || (s3 > 0.25f)) && (s0 < 0.25f);
        keys[m] = msk ? best : -1;
    }
}

// ---------------------------------------------------------------------------
// Kernel 5: stable counting sort by class descending (unchanged).
// ---------------------------------------------------------------------------
__global__ __launch_bounds__(64) void order_kernel(
    const int* __restrict__ keys, int* __restrict__ ord, int* __restrict__ cnts)
{
    const int b = blockIdx.x;
    const int lane = threadIdx.x;
    const int* kb = keys + b * LL;
    int c0 = 0, c1 = 0, c2 = 0, c3 = 0;
    for (int line = lane; line < LL; line += 64) {
        int k = kb[line];
        c0 += (k == 0); c1 += (k == 1); c2 += (k == 2); c3 += (k == 3);
    }
#pragma unroll
    for (int off = 32; off > 0; off >>= 1) {
        c0 += __shfl_down(c0, off, 64);
        c1 += __shfl_down(c1, off, 64);
        c2 += __shfl_down(c2, off, 64);
        c3 += __shfl_down(c3, off, 64);
    }
    int t0 = __shfl(c0, 0, 64), t1 = __shfl(c1, 0, 64);
    int t2 = __shfl(c2, 0, 64), t3 = __shfl(c3, 0, 64);
    if (lane == 0) cnts[b] = t0 + t1 + t2 + t3;
    int base[4];
    base[3] = 0; base[2] = t3; base[1] = t3 + t2; base[0] = t3 + t2 + t1;
    int run[4] = {0, 0, 0, 0};
    const unsigned long long below = (1ull << lane) - 1ull;
    int* ob = ord + b * LL;
    for (int s0 = 0; s0 < LL; s0 += 64) {
        int line = s0 + lane;
        int k = (line < LL) ? kb[line] : -2;
#pragma unroll
        for (int kk = 0; kk < 4; kk++) {
            unsigned long long mask = __ballot(k == kk);
            if (k == kk) {
                int pos = base[kk] + run[kk] + __popcll(mask & below);
                ob[pos] = line;
            }
            run[kk] += __popcll(mask);
        }
    }
}

// ---------------------------------------------------------------------------
// Kernel 6: cyclic fill of 2500 outputs per batch (unchanged).
// ---------------------------------------------------------------------------
__global__ __launch_bounds__(256) void fill_kernel(
    const float* __restrict__ lines, const float* __restrict__ s,
    const int* __restrict__ ord, const int* __restrict__ cnts,
    float* __restrict__ out)
{
    const int i = blockIdx.x * 256 + threadIdx.x;
    if (i >= BB * N_OUT_LINE) return;
    const int b = i / N_OUT_LINE;
    const int j = i % N_OUT_LINE;
    const int cnt = cnts[b];
    float4 lo = {0.f, 0.f, 0.f, 0.f}, sc = {0.f, 0.f, 0.f, 0.f};
    if (cnt > 0) {
        int line = ord[b * LL + (j % cnt)];
        lo = *(const float4*)(lines + ((size_t)b * LL + line) * 4);
        sc = *(const float4*)(s + ((size_t)b * LL + line) * 4);
    }
    *(float4*)(out + (size_t)i * 4) = lo;
    *(float4*)(out + (size_t)(BB * N_OUT_LINE) * 4 + (size_t)i * 4) = sc;
}

// ---------------------------------------------------------------------------
extern "C" void kernel_launch(void* const* d_in, const int* in_sizes, int n_in,
                              void* d_out, int out_size, void* d_ws, size_t ws_size,
                              hipStream_t stream) {
    (void)in_sizes; (void)n_in; (void)out_size; (void)ws_size;
    const float* feature = (const float*)d_in[0];
    const float* lines   = (const float*)d_in[1];
    const float* fc1_w   = (const float*)d_in[2];
    const float* fc1_b   = (const float*)d_in[3];
    const float* w1      = (const float*)d_in[4];
    const float* b1      = (const float*)d_in[5];
    const float* w2      = (const float*)d_in[6];
    const float* b2      = (const float*)d_in[7];
    const float* w3      = (const float*)d_in[8];
    const float* b3      = (const float*)d_in[9];
    float* out = (float*)d_out;

    float* x = (float*)d_ws;
    short* pooled_hi = (short*)(x + (size_t)BB * PIX * 128);
    short* pooled_lo = pooled_hi + (size_t)MM * DIM_FC;
    short* h1hi = (short*)x;
    short* h1lo = h1hi + (size_t)MM * DIM_FC;
    float* h2 = (float*)pooled_hi;
    short* w1hi = (short*)((char*)d_ws + 100u * 1024u * 1024u);
    short* w1lo = w1hi + DIM_FC * DIM_FC;
    short* w2hi = w1lo + DIM_FC * DIM_FC;
    short* w2lo = w2hi + DIM_FC * DIM_FC;
    float* s    = (float*)(pooled_lo + (size_t)MM * DIM_FC);
    int* keys   = (int*)(s + MM * 4);
    int* ord    = keys + MM;
    int* cnts   = ord + MM;
    short* fc1hi = (short*)(cnts + 64);
    short* fc1lo = fc1hi + DIM_LOI * C_IN;

    split_kernel<<<(DIM_LOI * C_IN) / 1024, 256, 0, stream>>>(fc1_w, fc1hi, fc1lo);
    conv_mfma_kernel<<<(BB * PIX) / 128, 256, 0, stream>>>(
        feature, fc1hi, fc1lo, fc1_b, x);
    sample_pool_kernel<<<MM, 128, 0, stream>>>(lines, x, pooled_hi, pooled_lo);
    split_kernel<<<DIM_FC * DIM_FC / 1024, 256, 0, stream>>>(w1, w1hi, w1lo);
    split_kernel<<<DIM_FC * DIM_FC / 1024, 256, 0, stream>>>(w2, w2hi, w2lo);

    // grid: Mtiles(79) x 8 N-tiles, 512 threads, bijective XCD swizzle in-kernel
    const int Mtiles = (MM + 255) / 256;   // 79
    gemm_bf16x3_v3<true><<<Mtiles * 8, 512, 0, stream>>>(
        pooled_hi, pooled_lo, w1hi, w1lo, b1, nullptr, h1hi, h1lo, MM, Mtiles);
    gemm_bf16x3_v3<false><<<Mtiles * 8, 512, 0, stream>>>(
        h1hi, h1lo, w2hi, w2lo, b2, h2, nullptr, nullptr, MM, Mtiles);

    fc3_softmax_kernel<<<MM / 4, 256, 0, stream>>>(h2, w3, b3, s, keys);
    order_kernel<<<BB, 64, 0, stream>>>(keys, ord, cnts);
    fill_kernel<<<(BB * N_OUT_LINE + 255) / 256, 256, 0, stream>>>(
        lines, s, ord, cnts, out);
}

// Round 2
// 890.246 us; speedup vs baseline: 1.0493x; 1.0493x over previous
//
#include <hip/hip_runtime.h>
#include <hip/hip_bf16.h>
#include <math.h>

// Problem constants
#define BB 4
#define C_IN 256
#define HH 256
#define WW 256
#define LL 5000
#define N_PTS0 32
#define N_PTS1 8
#define DIM_LOI 128
#define DIM_FC 1024
#define N_OUT_LINE 2500
#define MM (BB * LL)          // 20000
#define PIX (HH * WW)         // 65536

typedef __attribute__((ext_vector_type(8))) short short8_t;   // 8 bf16 in 4 VGPRs
typedef __attribute__((ext_vector_type(4))) float float4v;

// float -> bf16 (RNE) bit tricks
__device__ __forceinline__ short f2bf(float f) {
    union { float f; unsigned u; } c; c.f = f;
    unsigned u = c.u;
    u += 0x7FFFu + ((u >> 16) & 1u);
    return (short)(u >> 16);
}
__device__ __forceinline__ float bf2f(short h) {
    union { unsigned u; float f; } c; c.u = ((unsigned)(unsigned short)h) << 16;
    return c.f;
}

// async global->LDS DMA, 16 B per lane; dest = wave-uniform base + lane*16
__device__ __forceinline__ void load_lds16(const void* g, void* l) {
    __builtin_amdgcn_global_load_lds(
        (const __attribute__((address_space(1))) void*)g,
        (__attribute__((address_space(3))) void*)l, 16, 0, 0);
}

// raw barrier (NO vmcnt drain) with compiler-level memory fences so memory ops
// (ds_read / global_load_lds) cannot be moved across it
__device__ __forceinline__ void wave_barrier() {
    asm volatile("" ::: "memory");
    __builtin_amdgcn_s_barrier();
    asm volatile("" ::: "memory");
}

#define MFMA_B16(a, b, c) \
    c = __builtin_amdgcn_mfma_f32_16x16x32_bf16(a, b, c, 0, 0, 0)

// ---------------------------------------------------------------------------
// Kernel 1: 1x1 conv as bf16x3 MFMA GEMM (unchanged).
// ---------------------------------------------------------------------------
__global__ __launch_bounds__(256) void conv_mfma_kernel(
    const float* __restrict__ feat,   // [B, 256, PIX]
    const short* __restrict__ whi,    // [128, 256] bf16 hi
    const short* __restrict__ wlo,    // [128, 256] bf16 lo
    const float* __restrict__ bias,   // [128]
    float* __restrict__ x)            // [B*PIX, 128]
{
    __shared__ short As_hi[128][40];
    __shared__ short As_lo[128][40];
    __shared__ short Ws_hi[128][40];
    __shared__ short Ws_lo[128][40];

    const int t  = threadIdx.x;
    const int m0 = blockIdx.x * 128;
    const int b  = m0 >> 16;
    const int p0 = m0 & (PIX - 1);
    const float* fb = feat + (size_t)b * C_IN * PIX + p0;

    const int w = t >> 6, lane = t & 63;
    const int wmb = (w >> 1) * 64, wnb = (w & 1) * 64;
    const int fr = lane & 15;
    const int koff = (lane >> 4) << 3;

    const int sp = t & 127;
    const int cg = t >> 7;

    float4v acc[4][4];
#pragma unroll
    for (int mi = 0; mi < 4; mi++)
#pragma unroll
        for (int ni = 0; ni < 4; ni++)
            acc[mi][ni] = (float4v){0.f, 0.f, 0.f, 0.f};

    for (int k0 = 0; k0 < C_IN; k0 += 32) {
#pragma unroll
        for (int i = 0; i < 2; i++) {
            int idx = t + (i << 8);
            int row = idx >> 2;
            int kc  = (idx & 3) << 3;
            *(int4*)&Ws_hi[row][kc] = *(const int4*)(whi + row * C_IN + k0 + kc);
            *(int4*)&Ws_lo[row][kc] = *(const int4*)(wlo + row * C_IN + k0 + kc);
        }
#pragma unroll
        for (int j = 0; j < 8; j++) {
            int c = cg * 16 + j * 2;
            float v0 = fb[(size_t)(k0 + c) * PIX + sp];
            float v1 = fb[(size_t)(k0 + c + 1) * PIX + sp];
            short h0 = f2bf(v0), h1 = f2bf(v1);
            short l0 = f2bf(v0 - bf2f(h0)), l1 = f2bf(v1 - bf2f(h1));
            *(unsigned*)&As_hi[sp][c] =
                (unsigned)(unsigned short)h0 | ((unsigned)(unsigned short)h1 << 16);
            *(unsigned*)&As_lo[sp][c] =
                (unsigned)(unsigned short)l0 | ((unsigned)(unsigned short)l1 << 16);
        }
        __syncthreads();

        short8_t ah[4], al[4];
#pragma unroll
        for (int mi = 0; mi < 4; mi++) {
            ah[mi] = *(const short8_t*)&As_hi[wmb + mi * 16 + fr][koff];
            al[mi] = *(const short8_t*)&As_lo[wmb + mi * 16 + fr][koff];
        }
#pragma unroll
        for (int ni = 0; ni < 4; ni++) {
            short8_t bh = *(const short8_t*)&Ws_hi[wnb + ni * 16 + fr][koff];
            short8_t bl = *(const short8_t*)&Ws_lo[wnb + ni * 16 + fr][koff];
#pragma unroll
            for (int mi = 0; mi < 4; mi++) {
                MFMA_B16(ah[mi], bh, acc[mi][ni]);
                MFMA_B16(al[mi], bh, acc[mi][ni]);
                MFMA_B16(ah[mi], bl, acc[mi][ni]);
            }
        }
        __syncthreads();
    }

#pragma unroll
    for (int ni = 0; ni < 4; ni++) {
        int ncol = wnb + ni * 16 + fr;
        float bv = bias[ncol];
#pragma unroll
        for (int mi = 0; mi < 4; mi++) {
            int r0 = m0 + wmb + mi * 16 + ((lane >> 4) << 2);
#pragma unroll
            for (int i2 = 0; i2 < 4; i2++) {
                x[(size_t)(r0 + i2) * 128 + ncol] = acc[mi][ni][i2] + bv;
            }
        }
    }
}

// ---------------------------------------------------------------------------
// Kernel 2: bilinear sample + maxpool -> bf16 hi/lo pooled (unchanged).
// ---------------------------------------------------------------------------
__global__ __launch_bounds__(128) void sample_pool_kernel(
    const float* __restrict__ lines,
    const float* __restrict__ x,
    short* __restrict__ phi,
    short* __restrict__ plo)
{
    const int bl = blockIdx.x;
    const int b  = bl / LL;
    const int c  = threadIdx.x;
    const float* lp = lines + (size_t)bl * 4;
    const float p0r = lp[0], p0c = lp[1], p1r = lp[2], p1c = lp[3];
    const float* xb = x + (size_t)b * PIX * 128;

    short8_t vh, vl;
#pragma unroll
    for (int g = 0; g < 8; g++) {
        float mx = -INFINITY;
#pragma unroll
        for (int j = 0; j < 4; j++) {
            int tt = g * 4 + j;
            float lam = (float)((double)tt / 31.0);
            float px = p0r * lam + p1r * (1.0f - lam) - 0.5f;
            float py = p0c * lam + p1c * (1.0f - lam) - 0.5f;
            float px0 = fminf(fmaxf(floorf(px), 0.0f), 255.0f);
            float py0 = fminf(fmaxf(floorf(py), 0.0f), 255.0f);
            float px1 = fminf(px0 + 1.0f, 255.0f);
            float py1 = fminf(py0 + 1.0f, 255.0f);
            int ix0 = (int)px0, iy0 = (int)py0, ix1 = (int)px1, iy1 = (int)py1;
            float wx1 = px1 - px, wx0 = px - px0;
            float wy1 = py1 - py, wy0 = py - py0;
            float v00 = xb[(size_t)(ix0 * WW + iy0) * 128 + c];
            float v10 = xb[(size_t)(ix1 * WW + iy0) * 128 + c];
            float v01 = xb[(size_t)(ix0 * WW + iy1) * 128 + c];
            float v11 = xb[(size_t)(ix1 * WW + iy1) * 128 + c];
            float v = v00 * (wx1 * wy1) + v10 * (wx0 * wy1)
                    + v01 * (wx1 * wy0) + v11 * (wx0 * wy0);
            mx = fmaxf(mx, v);
        }
        short h = f2bf(mx);
        vh[g] = h;
        vl[g] = f2bf(mx - bf2f(h));
    }
    *(short8_t*)(phi + (size_t)bl * 1024 + c * 8) = vh;
    *(short8_t*)(plo + (size_t)bl * 1024 + c * 8) = vl;
}

// ---------------------------------------------------------------------------
// Kernel 2b: split fp32 weights into bf16 hi/lo (unchanged).
// ---------------------------------------------------------------------------
__global__ __launch_bounds__(256) void split_kernel(
    const float* __restrict__ w, short* __restrict__ hi, short* __restrict__ lo)
{
    const int i = (blockIdx.x * 256 + threadIdx.x) * 4;
    float4 v = *(const float4*)(w + i);
    float vv[4] = {v.x, v.y, v.z, v.w};
    short4 h, l;
    short hs[4], ls[4];
#pragma unroll
    for (int j = 0; j < 4; j++) {
        hs[j] = f2bf(vv[j]);
        ls[j] = f2bf(vv[j] - bf2f(hs[j]));
    }
    h.x = hs[0]; h.y = hs[1]; h.z = hs[2]; h.w = hs[3];
    l.x = ls[0]; l.y = ls[1]; l.z = ls[2]; l.w = ls[3];
    *(short4*)(hi + i) = h;
    *(short4*)(lo + i) = l;
}

// ---------------------------------------------------------------------------
// Kernel 3 v4: bf16x3 MFMA GEMM-NT, compiler-pipelined tile body.
//
//  Tile 192(M) x 256(N), BK=32, 512 threads (8 waves, 2M x 4N wave grid),
//  per-wave 96x64 output (acc[6][4]) -> 72 MFMA per 20 ds_read_b128 per tile
//  (ratio 3.6 vs 3.0 before).
//  NO intra-tile phase barriers: all 20 reads + 72 MFMA in one region; the
//  compiler's fine-grained lgkmcnt(N) overlaps the ~1250-cyc LDS read stream
//  under the ~2400-cyc MFMA stream (serializing them was the round-1 stall).
//  2 barriers/tile: (a) after MFMA = all reads of buf[cur] consumed, so DMA
//  for tile t+2 may overwrite it; (b) after counted s_waitcnt vmcnt(7) =
//  tile t+1 (issued a full tile ago, the 7 oldest loads) has landed while
//  t+2's 7 loads stay in flight. Never vmcnt(0) in steady state.
//  LDS: 2 buffers x 56 KB = 112 KB. T2 swizzle identical to v3 (0 conflicts):
//  linear DMA dest + source chunk pre-permute csrc, XOR'd read chunk ksw.
//  Bijective XCD chunking over M-major wgid: each XCD takes a contiguous run
//  of M-panels x all 4 N-tiles, so A-panels are fetched by one XCD only.
// ---------------------------------------------------------------------------
#define NT 32                 // K tiles (1024 / 32)
#define BUFS 28672            // shorts per buffer (56 KB)
#define A_LO 6144             // [192][32] hi at 0, lo at 6144
#define B_HI 12288            // [256][32] hi
#define B_LO 20480            // [256][32] lo

template <bool SPLIT_OUT>
__global__ __launch_bounds__(512, 2) void gemm_bf16x3_v4(
    const short* __restrict__ Ahi, const short* __restrict__ Alo,
    const short* __restrict__ Bhi, const short* __restrict__ Blo,
    const float* __restrict__ bias,
    float* __restrict__ Cf, short* __restrict__ Chi, short* __restrict__ Clo,
    int M, int Mtiles)
{
    __shared__ short lds[2 * BUFS];   // 112 KB

    const int t   = threadIdx.x;
    const int bid = blockIdx.x;
    // bijective XCD chunking (m204): nwg = Mtiles*4, xcd = bid&7
    const int nwg = Mtiles * 4;
    const int q = nwg >> 3, r = nwg & 7;
    const int xcd = bid & 7, seq = bid >> 3;
    const int wgid = ((xcd < r) ? xcd * (q + 1) : r * (q + 1) + (xcd - r) * q) + seq;
    const int tileM = wgid >> 2, tileN = wgid & 3;   // M-major: same-A adjacent
    const int m0 = tileM * 192, n0 = tileN * 256;

    const int w = t >> 6, lane = t & 63;
    const int wr = w >> 2;            // 0..1 -> M offset wr*96
    const int wc = w & 3;             // 0..3 -> N offset wc*64
    const int fr = lane & 15;
    // swizzled read chunk: (lane>>4) ^ ((row>>1)&3), row ≡ fr (mod 16)
    const int ksw = (((lane >> 4) ^ ((lane >> 1) & 3)) << 3);
    const int a_row = wr * 96 + fr;
    const int b_row = wc * 64 + fr;

    // --- DMA descriptors: 7 chunks/wave, 56 chunks = 56 KB per K-tile
    const short* gp[7];
    int lp[7];
    {
        const int csrc = (lane & 3) ^ ((lane >> 3) & 3);  // source chunk permute
#pragma unroll
        for (int s = 0; s < 7; s++) {
            int e = w * 7 + s;                            // 0..55
            const short* mp; int mo, j, grow;
            int rl = lane >> 2;                           // row within 16-row chunk
            if (e < 12)      { mp = Ahi; mo = 0;    j = e;      grow = min(m0 + j * 16 + rl, M - 1); }
            else if (e < 24) { mp = Alo; mo = A_LO; j = e - 12; grow = min(m0 + j * 16 + rl, M - 1); }
            else if (e < 40) { mp = Bhi; mo = B_HI; j = e - 24; grow = n0 + j * 16 + rl; }
            else             { mp = Blo; mo = B_LO; j = e - 40; grow = n0 + j * 16 + rl; }
            gp[s] = mp + (size_t)grow * 1024 + csrc * 8;
            lp[s] = mo + j * 512 + lane * 8;              // linear dest, lane*16B
        }
    }

    // --- prologue: tile0 -> buf0, tile1 -> buf1; wait tile0 only (vmcnt(7))
#pragma unroll
    for (int s = 0; s < 7; s++) { load_lds16(gp[s], &lds[lp[s]]); gp[s] += 32; }
#pragma unroll
    for (int s = 0; s < 7; s++) { load_lds16(gp[s], &lds[BUFS + lp[s]]); gp[s] += 32; }
    asm volatile("s_waitcnt vmcnt(7)" ::: "memory");
    wave_barrier();

    float4v acc[6][4];
#pragma unroll
    for (int mf = 0; mf < 6; mf++)
#pragma unroll
        for (int nf = 0; nf < 4; nf++)
            acc[mf][nf] = (float4v){0.f, 0.f, 0.f, 0.f};

    for (int kt = 0; kt < NT; ++kt) {
        const int off = (kt & 1) * BUFS;

        // B fragments for the whole tile (8 reads), then per-M-frag A reads;
        // no lgkmcnt(0) pin: compiler interleaves MFMA with in-flight reads.
        short8_t bh[4], bl[4];
#pragma unroll
        for (int nf = 0; nf < 4; nf++) {
            bh[nf] = *(const short8_t*)&lds[off + B_HI + (b_row + nf * 16) * 32 + ksw];
            bl[nf] = *(const short8_t*)&lds[off + B_LO + (b_row + nf * 16) * 32 + ksw];
        }
#pragma unroll
        for (int mf = 0; mf < 6; mf++) {
            short8_t ah = *(const short8_t*)&lds[off + (a_row + mf * 16) * 32 + ksw];
            short8_t al = *(const short8_t*)&lds[off + A_LO + (a_row + mf * 16) * 32 + ksw];
#pragma unroll
            for (int nf = 0; nf < 4; nf++) {
                MFMA_B16(ah, bh[nf], acc[mf][nf]);
                MFMA_B16(al, bh[nf], acc[mf][nf]);
                MFMA_B16(ah, bl[nf], acc[mf][nf]);
            }
        }

        if (kt < NT - 1) {
            wave_barrier();               // all reads of buf[cur] consumed
            if (kt + 2 < NT) {
                // stage tile kt+2 into buf[cur]; lands during tile kt+1
#pragma unroll
                for (int s = 0; s < 7; s++) {
                    load_lds16(gp[s], &lds[off + lp[s]]); gp[s] += 32;
                }
                asm volatile("s_waitcnt vmcnt(7)" ::: "memory");  // kt+1 landed
            } else {
                asm volatile("s_waitcnt vmcnt(0)" ::: "memory");  // drain last
            }
            wave_barrier();               // publish buf for tile kt+1
        }
    }

    // ---- epilogue
#pragma unroll
    for (int nf = 0; nf < 4; nf++) {
        int ncol = n0 + wc * 64 + nf * 16 + fr;
        float bv = bias[ncol];
#pragma unroll
        for (int mf = 0; mf < 6; mf++) {
            int r0 = m0 + wr * 96 + mf * 16 + ((lane >> 4) << 2);
#pragma unroll
            for (int i2 = 0; i2 < 4; i2++) {
                int rr = r0 + i2;
                if (rr < M) {
                    float v = fmaxf(acc[mf][nf][i2] + bv, 0.0f);
                    if (SPLIT_OUT) {
                        short h = f2bf(v);
                        Chi[(size_t)rr * 1024 + ncol] = h;
                        Clo[(size_t)rr * 1024 + ncol] = f2bf(v - bf2f(h));
                    } else {
                        Cf[(size_t)rr * 1024 + ncol] = v;
                    }
                }
            }
        }
    }
}

// ---------------------------------------------------------------------------
// Kernel 4: fc3 (N=4) + softmax + mask + argmax-class key (unchanged).
// ---------------------------------------------------------------------------
__global__ __launch_bounds__(256) void fc3_softmax_kernel(
    const float* __restrict__ h2, const float* __restrict__ w3,
    const float* __restrict__ b3, float* __restrict__ s, int* __restrict__ keys)
{
    const int m = blockIdx.x * 4 + (threadIdx.x >> 6);
    const int lane = threadIdx.x & 63;
    const float* hp = h2 + (size_t)m * DIM_FC;
    float a0 = 0.f, a1 = 0.f, a2 = 0.f, a3 = 0.f;
    for (int k = lane; k < DIM_FC; k += 64) {
        float hv = hp[k];
        a0 = fmaf(hv, w3[k], a0);
        a1 = fmaf(hv, w3[DIM_FC + k], a1);
        a2 = fmaf(hv, w3[2 * DIM_FC + k], a2);
        a3 = fmaf(hv, w3[3 * DIM_FC + k], a3);
    }
#pragma unroll
    for (int off = 32; off > 0; off >>= 1) {
        a0 += __shfl_down(a0, off, 64);
        a1 += __shfl_down(a1, off, 64);
        a2 += __shfl_down(a2, off, 64);
        a3 += __shfl_down(a3, off, 64);
    }
    if (lane == 0) {
        float l0 = a0 + b3[0], l1 = a1 + b3[1], l2 = a2 + b3[2], l3 = a3 + b3[3];
        float mxl = fmaxf(fmaxf(l0, l1), fmaxf(l2, l3));
        float e0 = expf(l0 - mxl), e1 = expf(l1 - mxl);
        float e2 = expf(l2 - mxl), e3 = expf(l3 - mxl);
        float inv = 1.0f / (e0 + e1 + e2 + e3);
        float s0 = e0 * inv, s1 = e1 * inv, s2 = e2 * inv, s3 = e3 * inv;
        float* sp = s + (size_t)m * 4;
        sp[0] = s0; sp[1] = s1; sp[2] = s2; sp[3] = s3;
        int best = 0; float bv = s0;
        if (s1 > bv) { best = 1; bv = s1; }
        if (s2 > bv) { best = 2; bv = s2; }
        if (s3 > bv) { best = 3; bv = s3; }
        bool msk = ((s1 > 0.25f) || (s2 > 0.25f) || (s3 > 0.25f)) && (s0 < 0.25f);
        keys[m] = msk ? best : -1;
    }
}

// ---------------------------------------------------------------------------
// Kernel 5: stable counting sort by class descending (unchanged).
// ---------------------------------------------------------------------------
__global__ __launch_bounds__(64) void order_kernel(
    const int* __restrict__ keys, int* __restrict__ ord, int* __restrict__ cnts)
{
    const int b = blockIdx.x;
    const int lane = threadIdx.x;
    const int* kb = keys + b * LL;
    int c0 = 0, c1 = 0, c2 = 0, c3 = 0;
    for (int line = lane; line < LL; line += 64) {
        int k = kb[line];
        c0 += (k == 0); c1 += (k == 1); c2 += (k == 2); c3 += (k == 3);
    }
#pragma unroll
    for (int off = 32; off > 0; off >>= 1) {
        c0 += __shfl_down(c0, off, 64);
        c1 += __shfl_down(c1, off, 64);
        c2 += __shfl_down(c2, off, 64);
        c3 += __shfl_down(c3, off, 64);
    }
    int t0 = __shfl(c0, 0, 64), t1 = __shfl(c1, 0, 64);
    int t2 = __shfl(c2, 0, 64), t3 = __shfl(c3, 0, 64);
    if (lane == 0) cnts[b] = t0 + t1 + t2 + t3;
    int base[4];
    base[3] = 0; base[2] = t3; base[1] = t3 + t2; base[0] = t3 + t2 + t1;
    int run[4] = {0, 0, 0, 0};
    const unsigned long long below = (1ull << lane) - 1ull;
    int* ob = ord + b * LL;
    for (int s0 = 0; s0 < LL; s0 += 64) {
        int line = s0 + lane;
        int k = (line < LL) ? kb[line] : -2;
#pragma unroll
        for (int kk = 0; kk < 4; kk++) {
            unsigned long long mask = __ballot(k == kk);
            if (k == kk) {
                int pos = base[kk] + run[kk] + __popcll(mask & below);
                ob[pos] = line;
            }
            run[kk] += __popcll(mask);
        }
    }
}

// ---------------------------------------------------------------------------
// Kernel 6: cyclic fill of 2500 outputs per batch (unchanged).
// ---------------------------------------------------------------------------
__global__ __launch_bounds__(256) void fill_kernel(
    const float* __restrict__ lines, const float* __restrict__ s,
    const int* __restrict__ ord, const int* __restrict__ cnts,
    float* __restrict__ out)
{
    const int i = blockIdx.x * 256 + threadIdx.x;
    if (i >= BB * N_OUT_LINE) return;
    const int b = i / N_OUT_LINE;
    const int j = i % N_OUT_LINE;
    const int cnt = cnts[b];
    float4 lo = {0.f, 0.f, 0.f, 0.f}, sc = {0.f, 0.f, 0.f, 0.f};
    if (cnt > 0) {
        int line = ord[b * LL + (j % cnt)];
        lo = *(const float4*)(lines + ((size_t)b * LL + line) * 4);
        sc = *(const float4*)(s + ((size_t)b * LL + line) * 4);
    }
    *(float4*)(out + (size_t)i * 4) = lo;
    *(float4*)(out + (size_t)(BB * N_OUT_LINE) * 4 + (size_t)i * 4) = sc;
}

// ---------------------------------------------------------------------------
extern "C" void kernel_launch(void* const* d_in, const int* in_sizes, int n_in,
                              void* d_out, int out_size, void* d_ws, size_t ws_size,
                              hipStream_t stream) {
    (void)in_sizes; (void)n_in; (void)out_size; (void)ws_size;
    const float* feature = (const float*)d_in[0];
    const float* lines   = (const float*)d_in[1];
    const float* fc1_w   = (const float*)d_in[2];
    const float* fc1_b   = (const float*)d_in[3];
    const float* w1      = (const float*)d_in[4];
    const float* b1      = (const float*)d_in[5];
    const float* w2      = (const float*)d_in[6];
    const float* b2      = (const float*)d_in[7];
    const float* w3      = (const float*)d_in[8];
    const float* b3      = (const float*)d_in[9];
    float* out = (float*)d_out;

    float* x = (float*)d_ws;
    short* pooled_hi = (short*)(x + (size_t)BB * PIX * 128);
    short* pooled_lo = pooled_hi + (size_t)MM * DIM_FC;
    short* h1hi = (short*)x;
    short* h1lo = h1hi + (size_t)MM * DIM_FC;
    float* h2 = (float*)pooled_hi;
    short* w1hi = (short*)((char*)d_ws + 100u * 1024u * 1024u);
    short* w1lo = w1hi + DIM_FC * DIM_FC;
    short* w2hi = w1lo + DIM_FC * DIM_FC;
    short* w2lo = w2hi + DIM_FC * DIM_FC;
    float* s    = (float*)(pooled_lo + (size_t)MM * DIM_FC);
    int* keys   = (int*)(s + MM * 4);
    int* ord    = keys + MM;
    int* cnts   = ord + MM;
    short* fc1hi = (short*)(cnts + 64);
    short* fc1lo = fc1hi + DIM_LOI * C_IN;

    split_kernel<<<(DIM_LOI * C_IN) / 1024, 256, 0, stream>>>(fc1_w, fc1hi, fc1lo);
    conv_mfma_kernel<<<(BB * PIX) / 128, 256, 0, stream>>>(
        feature, fc1hi, fc1lo, fc1_b, x);
    sample_pool_kernel<<<MM, 128, 0, stream>>>(lines, x, pooled_hi, pooled_lo);
    split_kernel<<<DIM_FC * DIM_FC / 1024, 256, 0, stream>>>(w1, w1hi, w1lo);
    split_kernel<<<DIM_FC * DIM_FC / 1024, 256, 0, stream>>>(w2, w2hi, w2lo);

    // grid: Mtiles(105) x 4 N-tiles, 512 threads
    const int Mtiles = (MM + 191) / 192;   // 105
    gemm_bf16x3_v4<true><<<Mtiles * 4, 512, 0, stream>>>(
        pooled_hi, pooled_lo, w1hi, w1lo, b1, nullptr, h1hi, h1lo, MM, Mtiles);
    gemm_bf16x3_v4<false><<<Mtiles * 4, 512, 0, stream>>>(
        h1hi, h1lo, w2hi, w2lo, b2, h2, nullptr, nullptr, MM, Mtiles);

    fc3_softmax_kernel<<<MM / 4, 256, 0, stream>>>(h2, w3, b3, s, keys);
    order_kernel<<<BB, 64, 0, stream>>>(keys, ord, cnts);
    fill_kernel<<<(BB * N_OUT_LINE + 255) / 256, 256, 0, stream>>>(
        lines, s, ord, cnts, out);
}